// Round 1
// 816.898 us; speedup vs baseline: 1.9459x; 1.9459x over previous
//
#include <hip/hip_runtime.h>
#include <hip/hip_bf16.h>

typedef unsigned int uint32;
typedef unsigned short ushort16;
typedef __attribute__((ext_vector_type(8))) __bf16 bf16x8;
typedef __attribute__((ext_vector_type(4))) float f32x4;

__device__ __forceinline__ ushort16 f2bf(float f) {
    uint32 u = __float_as_uint(f);
    u += 0x7fff + ((u >> 16) & 1);       // round-to-nearest-even
    return (ushort16)(u >> 16);
}
// pack two fp32 -> dword of 2 bf16 (a in low half), round-to-nearest (+0x8000)
__device__ __forceinline__ uint32 pack2rn(float a, float b) {
    uint32 ua = __float_as_uint(a) + 0x8000u;
    uint32 ub = __float_as_uint(b) + 0x8000u;
    return __builtin_amdgcn_perm(ub, ua, 0x07060302);  // [a.hi16, b.hi16]
}
__device__ __forceinline__ float blo(uint32 u) { return __uint_as_float(u << 16); }
__device__ __forceinline__ float bhi(uint32 u) { return __uint_as_float(u & 0xffff0000u); }

__device__ __forceinline__ void storeC(float v, float* p) { *p = v; }
__device__ __forceinline__ void storeC(float v, ushort16* p) { *p = f2bf(v); }

// ---------------------------------------------------------------------------
// MFMA GEMM: C[M,N] = A[M,K](fp32) @ W[K,*](fp32) + bias, out OutT (fp32|bf16).
// 128x128 tile, BK=64, 4 waves x (4x4 grid of 16x16x32 bf16 MFMA).
// LDS: As[m][k] / Bs[n][k] bf16, 16B-chunk XOR swizzle (c_phys = c ^ (row&7))
// -> conflict-free ds_read_b128 fragments.  W split: cols < nsplit from W1
// (width ldw), else W2 (supports fused K|V GEMM).
// ---------------------------------------------------------------------------
template <typename OutT>
__global__ __launch_bounds__(256) void gemm_mfma(
    const float* __restrict__ A, const float* __restrict__ W1,
    const float* __restrict__ W2, int ldw,
    const float* __restrict__ b1, const float* __restrict__ b2,
    OutT* __restrict__ C, int N, int K, int nsplit)
{
    __shared__ ushort16 As[128 * 64];
    __shared__ ushort16 Bs[128 * 64];

    const int tid  = threadIdx.x;
    const int lane = tid & 63, wave = tid >> 6;
    const int quad = lane >> 4, m16 = lane & 15;
    const int wm = (wave >> 1) * 64, wn = (wave & 1) * 64;
    const int gm0 = blockIdx.y * 128, gn0 = blockIdx.x * 128;

    const float* Wuse = (gn0 < nsplit) ? W1 : W2;
    const int ncol0 = (gn0 < nsplit) ? gn0 : gn0 - nsplit;

    f32x4 acc[4][4];
#pragma unroll
    for (int i = 0; i < 4; ++i)
#pragma unroll
        for (int j = 0; j < 4; ++j) acc[i][j] = (f32x4){0.f, 0.f, 0.f, 0.f};

    // staging geometry
    const int ra = tid >> 3, cla = tid & 7;            // A: row, logical k-chunk
    const int kpb = tid >> 5, nlb = tid & 31;          // B: k-pair, n-lane
    const float* Ap = A + (size_t)(gm0 + ra) * K + cla * 8;
    const float* Wp = Wuse + (size_t)(2 * kpb) * ldw + ncol0 + nlb;

    for (int k0 = 0; k0 < K; k0 += 64) {
        float4 av0[4], av1[4];
        float bv0[4][4], bv1[4][4];
#pragma unroll
        for (int t = 0; t < 4; ++t) {
            const float* ap = Ap + k0 + (size_t)(32 * t) * K;
            av0[t] = *(const float4*)ap;
            av1[t] = *(const float4*)(ap + 4);
            const float* wp = Wp + (size_t)(k0 + 16 * t) * ldw;
#pragma unroll
            for (int j = 0; j < 4; ++j) {
                bv0[t][j] = wp[32 * j];
                bv1[t][j] = wp[(size_t)ldw + 32 * j];
            }
        }
        __syncthreads();   // previous tile fully consumed
#pragma unroll
        for (int t = 0; t < 4; ++t) {
            int r = ra + 32 * t;
            uint4 st;
            st.x = pack2rn(av0[t].x, av0[t].y);
            st.y = pack2rn(av0[t].z, av0[t].w);
            st.z = pack2rn(av1[t].x, av1[t].y);
            st.w = pack2rn(av1[t].z, av1[t].w);
            *(uint4*)&As[r * 64 + ((cla ^ (r & 7)) * 8)] = st;

            int kp = kpb + 8 * t;
            int clb = kp >> 2, kq = kp & 3;
#pragma unroll
            for (int j = 0; j < 4; ++j) {
                int n = nlb + 32 * j;
                *(uint32*)&Bs[n * 64 + (clb ^ (n & 7)) * 8 + kq * 2] =
                    pack2rn(bv0[t][j], bv1[t][j]);
            }
        }
        __syncthreads();

#pragma unroll
        for (int s = 0; s < 2; ++s) {
            bf16x8 aF[4], bF[4];
            const int cl = s * 4 + quad;
#pragma unroll
            for (int i = 0; i < 4; ++i) {
                int r = wm + i * 16 + m16;
                aF[i] = *(const bf16x8*)&As[r * 64 + (cl ^ (r & 7)) * 8];
                int n = wn + i * 16 + m16;
                bF[i] = *(const bf16x8*)&Bs[n * 64 + (cl ^ (n & 7)) * 8];
            }
#pragma unroll
            for (int i = 0; i < 4; ++i)
#pragma unroll
                for (int j = 0; j < 4; ++j)
                    acc[i][j] = __builtin_amdgcn_mfma_f32_16x16x32_bf16(
                        aF[i], bF[j], acc[i][j], 0, 0, 0);
        }
    }

    // epilogue: D row = quad*4 + reg, col = lane&15
#pragma unroll
    for (int j = 0; j < 4; ++j) {
        int col = gn0 + wn + j * 16 + m16;
        float bb = (col < nsplit) ? b1[col] : b2[col - nsplit];
#pragma unroll
        for (int i = 0; i < 4; ++i) {
            int row0 = gm0 + wm + i * 16 + quad * 4;
#pragma unroll
            for (int r = 0; r < 4; ++r)
                storeC(acc[i][j][r] + bb, C + (size_t)(row0 + r) * N + col);
        }
    }
}

// ---------------------------------------------------------------------------
// RoPE in-place on fp32 Q viewed as [S, 32, 128]; interleaved pairs.
// ---------------------------------------------------------------------------
__global__ void rope_q_kernel(float* __restrict__ T, int S)
{
    int idx = blockIdx.x * blockDim.x + threadIdx.x;
    if (idx >= S * 32 * 64) return;
    int i   = idx & 63;
    int rem = idx >> 6;       // s*32 + h
    int s   = rem >> 5;
    float inv = powf(5000.0f, -(float)i / 64.0f);
    float ang = (float)s * inv;
    float cs = cosf(ang), sn = sinf(ang);
    size_t base = (size_t)rem * 128 + 2 * i;
    float tr = T[base], ti = T[base + 1];
    T[base]     = tr * cs - ti * sn;
    T[base + 1] = tr * sn + ti * cs;
}

// RoPE in-place on bf16 K = cols 0..1023 of KVb [S][2048]
__global__ void rope_k_kernel(ushort16* __restrict__ KVb, int S)
{
    int idx = blockIdx.x * blockDim.x + threadIdx.x;
    if (idx >= S * 8 * 64) return;
    int i   = idx & 63;
    int rem = idx >> 6;       // s*8 + h
    int s   = rem >> 3, h = rem & 7;
    float inv = powf(5000.0f, -(float)i / 64.0f);
    float ang = (float)s * inv;
    float cs = cosf(ang), sn = sinf(ang);
    uint32* p = (uint32*)&KVb[(size_t)s * 2048 + h * 128 + 2 * i];
    uint32 u = *p;
    float tr = blo(u), ti = bhi(u);
    *p = pack2rn(tr * cs - ti * sn, tr * sn + ti * cs);
}

// ---------------------------------------------------------------------------
// MFMA flash attention. Block = (64-row q-tile, head); 256 threads = 4 waves.
// Q fp32 [S][4096]; KVb bf16 [S][2048] = K|V fused; O fp32 [S][4096].
// Wave w owns q-rows w*16..w*16+15 (A-frag rows = lane&15; D rows = quad*4+r).
// Fragment conventions identical to gemm_mfma above:
//   A = [row][k] bf16, 16B chunks, chunk_phys = chunk ^ (row&7)
//   B = [col][k] bf16, same swizzle;  C/D: col = lane&15, row = quad*4+reg.
// LDS: Ks[64][128] (K rows = B-operand of QK^T), Vt[128][64] (V^T = B-operand
// of PV), Ps[64][64] (P, wave-private rows -> no barrier between write/read).
// 40 KB LDS/block -> up to 4 blocks/CU.
// ---------------------------------------------------------------------------
__global__ __launch_bounds__(256) void flash_attn_kernel(
    const float* __restrict__ Q, const ushort16* __restrict__ KVb,
    float* __restrict__ O)
{
    __shared__ __align__(16) ushort16 Ks[64 * 128];   // [kv][d], swizzled
    __shared__ __align__(16) ushort16 Vt[128 * 64];   // [d][kv], swizzled
    __shared__ __align__(16) ushort16 Ps[64 * 64];    // [q][kv], swizzled

    const int tid  = threadIdx.x;
    const int lane = tid & 63, wave = tid >> 6;
    const int quad = lane >> 4, m16 = lane & 15;
    const int h = (int)blockIdx.y, kvh = h >> 2;
    const int q0 = (31 - (int)blockIdx.x) * 64;   // long blocks dispatch first
    const float scale = 0.08838834764831845f;     // 1/sqrt(128)

    const ushort16* Kbase = KVb + kvh * 128;
    const ushort16* Vbase = KVb + 1024 + kvh * 128;

    // Q A-fragments straight to registers: row = wave*16+m16, k = ks*32+quad*8+i
    bf16x8 qa[4];
    {
        const float* qp = Q + (size_t)(q0 + wave * 16 + m16) * 4096 + h * 128 + quad * 8;
#pragma unroll
        for (int ks = 0; ks < 4; ++ks) {
            float4 a = *(const float4*)(qp + ks * 32);
            float4 b = *(const float4*)(qp + ks * 32 + 4);
            uint4 u;
            u.x = pack2rn(a.x * scale, a.y * scale);
            u.y = pack2rn(a.z * scale, a.w * scale);
            u.z = pack2rn(b.x * scale, b.y * scale);
            u.w = pack2rn(b.z * scale, b.w * scale);
            qa[ks] = *(bf16x8*)&u;
        }
    }

    f32x4 acc_o[8];
#pragma unroll
    for (int t = 0; t < 8; ++t) acc_o[t] = (f32x4){0.f, 0.f, 0.f, 0.f};
    float m_i[4], l_i[4];
#pragma unroll
    for (int r = 0; r < 4; ++r) { m_i[r] = -1e30f; l_i[r] = 0.f; }

    for (int k0 = 0; k0 <= q0; k0 += 64) {
        __syncthreads();   // prev QK^T (Ks) and PV (Vt) reads complete

        // stage K -> Ks[kv][d]: straight 16B copies, swizzled dest
#pragma unroll
        for (int it = 0; it < 4; ++it) {
            int idx = tid + it * 256;
            int row = idx >> 4, c = idx & 15;
            *(uint4*)&Ks[row * 128 + ((c ^ (row & 7)) * 8)] =
                *(const uint4*)(Kbase + (size_t)(k0 + row) * 2048 + c * 8);
        }
        // stage V -> Vt[d][kv] via v_perm pair interleave.
        // rp = lane&31: a wave's 32 lanes cover a full 128B LDS row per write
        // (conflict-free); d-pairs per thread keep the global read as uint4.
#pragma unroll
        for (int it = 0; it < 2; ++it) {
            int idx = tid + it * 256;
            int rp  = idx & 31;           // kv row-pair 0..31
            int dcb = (idx >> 5) * 8;     // d base 0..120
            const ushort16* p0 = Vbase + (size_t)(k0 + 2 * rp) * 2048 + dcb;
            uint4 a = *(const uint4*)p0;
            uint4 b = *(const uint4*)(p0 + 2048);
            uint32 aw[4] = {a.x, a.y, a.z, a.w}, bw[4] = {b.x, b.y, b.z, b.w};
            int cc = rp >> 2, cbase = 2 * (rp & 3);
#pragma unroll
            for (int t = 0; t < 4; ++t) {
                int d0 = dcb + 2 * t, d1 = d0 + 1;
                *(uint32*)&Vt[d0 * 64 + ((cc ^ (d0 & 7)) * 8) + cbase] =
                    __builtin_amdgcn_perm(bw[t], aw[t], 0x05040100);
                *(uint32*)&Vt[d1 * 64 + ((cc ^ (d1 & 7)) * 8) + cbase] =
                    __builtin_amdgcn_perm(bw[t], aw[t], 0x07060302);
            }
        }
        __syncthreads();

        // S = Q @ K^T : wave strip 16(q) x 64(kv), 16 MFMAs
        f32x4 sacc[4];
#pragma unroll
        for (int j = 0; j < 4; ++j) sacc[j] = (f32x4){0.f, 0.f, 0.f, 0.f};
        __builtin_amdgcn_s_setprio(1);
#pragma unroll
        for (int ks = 0; ks < 4; ++ks) {
#pragma unroll
            for (int j = 0; j < 4; ++j) {
                int n = j * 16 + m16;
                bf16x8 kb = *(const bf16x8*)&Ks[n * 128 + (((ks * 4 + quad) ^ (n & 7)) * 8)];
                sacc[j] = __builtin_amdgcn_mfma_f32_16x16x32_bf16(qa[ks], kb, sacc[j], 0, 0, 0);
            }
        }
        __builtin_amdgcn_s_setprio(0);

        if (k0 == q0) {   // diagonal tile: causal mask
            int qr = wave * 16 + quad * 4;
#pragma unroll
            for (int j = 0; j < 4; ++j) {
                int kvl = j * 16 + m16;
#pragma unroll
                for (int r = 0; r < 4; ++r)
                    if (kvl > qr + r) sacc[j][r] = -1e30f;
            }
        }

        // online softmax (row group = 16 lanes of this quad, shfl butterfly)
#pragma unroll
        for (int r = 0; r < 4; ++r) {
            float rm = fmaxf(fmaxf(sacc[0][r], sacc[1][r]), fmaxf(sacc[2][r], sacc[3][r]));
            rm = fmaxf(rm, __shfl_xor(rm, 1));
            rm = fmaxf(rm, __shfl_xor(rm, 2));
            rm = fmaxf(rm, __shfl_xor(rm, 4));
            rm = fmaxf(rm, __shfl_xor(rm, 8));
            float mnew = fmaxf(m_i[r], rm);
            float al = __expf(m_i[r] - mnew);
            float rs = 0.f;
#pragma unroll
            for (int j = 0; j < 4; ++j) {
                float pv = __expf(sacc[j][r] - mnew);
                sacc[j][r] = pv;
                rs += pv;
            }
            rs += __shfl_xor(rs, 1);
            rs += __shfl_xor(rs, 2);
            rs += __shfl_xor(rs, 4);
            rs += __shfl_xor(rs, 8);
            l_i[r] = l_i[r] * al + rs;
            m_i[r] = mnew;
            int q = wave * 16 + quad * 4 + r;
#pragma unroll
            for (int j = 0; j < 4; ++j) {      // P -> Ps (wave-private rows)
                int kv = j * 16 + m16;
                Ps[q * 64 + (((kv >> 3) ^ (q & 7)) * 8) + (kv & 7)] = f2bf(sacc[j][r]);
            }
#pragma unroll
            for (int t = 0; t < 8; ++t) acc_o[t][r] *= al;
        }

        // O += P @ V : 16 MFMAs (A = Ps rows wave*16+m16, B = Vt)
        int qrow = wave * 16 + m16;
#pragma unroll
        for (int ks2 = 0; ks2 < 2; ++ks2) {
            bf16x8 pa = *(const bf16x8*)&Ps[qrow * 64 + (((ks2 * 4 + quad) ^ (qrow & 7)) * 8)];
            __builtin_amdgcn_s_setprio(1);
#pragma unroll
            for (int t = 0; t < 8; ++t) {
                int d = t * 16 + m16;
                bf16x8 vb = *(const bf16x8*)&Vt[d * 64 + (((ks2 * 4 + quad) ^ (d & 7)) * 8)];
                acc_o[t] = __builtin_amdgcn_mfma_f32_16x16x32_bf16(pa, vb, acc_o[t], 0, 0, 0);
            }
            __builtin_amdgcn_s_setprio(0);
        }
    }

    // epilogue: O /= l.  row = q0 + wave*16 + quad*4 + r, col = h*128 + t*16 + m16
    float* op = O + (size_t)(q0 + wave * 16 + quad * 4) * 4096 + h * 128 + m16;
#pragma unroll
    for (int r = 0; r < 4; ++r) {
        float inv = 1.0f / l_i[r];
#pragma unroll
        for (int t = 0; t < 8; ++t)
            op[(size_t)r * 4096 + t * 16] = acc_o[t][r] * inv;
    }
}

// ---------------------------------------------------------------------------
extern "C" void kernel_launch(void* const* d_in, const int* in_sizes, int n_in,
                              void* d_out, int out_size, void* d_ws, size_t ws_size,
                              hipStream_t stream)
{
    const float* x  = (const float*)d_in[0];
    const float* y  = (const float*)d_in[1];
    const float* Wq = (const float*)d_in[2];
    const float* bq = (const float*)d_in[3];
    const float* Wk = (const float*)d_in[4];
    const float* bk = (const float*)d_in[5];
    const float* Wv = (const float*)d_in[6];
    const float* bv = (const float*)d_in[7];
    const float* Wo = (const float*)d_in[8];
    const float* bo = (const float*)d_in[9];
    float* out = (float*)d_out;

    const int S = 2048, D = 4096;

    // Q fp32 lives in d_out (consumed by attn before final GEMM overwrites).
    float* Q = out;
    char* ws = (char*)d_ws;
    float*    Ao  = (float*)ws;                            // 32 MB fp32
    ushort16* KVb = (ushort16*)(ws + 34ull * 1024 * 1024); // 8 MB bf16 [S][2048]

    // Q = x @ Wq + bq   (fp32 out, 512 blocks)
    gemm_mfma<float><<<dim3(32, 16), 256, 0, stream>>>(
        x, Wq, Wq, D, bq, bq, Q, D, D, D);
    // KV = y @ [Wk|Wv] + [bk|bv]  (bf16 out, fused N=2048)
    gemm_mfma<ushort16><<<dim3(16, 16), 256, 0, stream>>>(
        y, Wk, Wv, 1024, bk, bv, KVb, 2048, D, 1024);

    rope_q_kernel<<<(S * 32 * 64 + 255) / 256, 256, 0, stream>>>(Q, S);
    rope_k_kernel<<<(S * 8 * 64 + 255) / 256, 256, 0, stream>>>(KVb, S);

    flash_attn_kernel<<<dim3(32, 32), 256, 0, stream>>>(Q, KVb, Ao);

    // out = Ao @ Wo + bo
    gemm_mfma<float><<<dim3(32, 16), 256, 0, stream>>>(
        Ao, Wo, Wo, D, bo, bo, out, D, D, D);
}

// Round 2
// 681.410 us; speedup vs baseline: 2.3328x; 1.1988x over previous
//
#include <hip/hip_runtime.h>
#include <hip/hip_bf16.h>

typedef unsigned int uint32;
typedef unsigned short ushort16;
typedef __attribute__((ext_vector_type(8))) __bf16 bf16x8;
typedef __attribute__((ext_vector_type(4))) float f32x4;

__device__ __forceinline__ ushort16 f2bf(float f) {
    uint32 u = __float_as_uint(f);
    u += 0x7fff + ((u >> 16) & 1);       // round-to-nearest-even
    return (ushort16)(u >> 16);
}
// pack two fp32 -> dword of 2 bf16 (a in low half), round-to-nearest (+0x8000)
__device__ __forceinline__ uint32 pack2rn(float a, float b) {
    uint32 ua = __float_as_uint(a) + 0x8000u;
    uint32 ub = __float_as_uint(b) + 0x8000u;
    return __builtin_amdgcn_perm(ub, ua, 0x07060302);  // [a.hi16, b.hi16]
}
__device__ __forceinline__ float blo(uint32 u) { return __uint_as_float(u << 16); }
__device__ __forceinline__ float bhi(uint32 u) { return __uint_as_float(u & 0xffff0000u); }

__device__ __forceinline__ void storeC(float v, float* p) { *p = v; }
__device__ __forceinline__ void storeC(float v, ushort16* p) { *p = f2bf(v); }

// ---------------------------------------------------------------------------
// MFMA GEMM: C[M,N] = A[M,K](fp32) @ W[K,*](fp32) + bias, out OutT (fp32|bf16).
// 128x128 tile, BK=64, 4 waves x (4x4 grid of 16x16x32 bf16 MFMA).
// LDS: As[m][k] / Bs[n][k] bf16, 16B-chunk XOR swizzle (c_phys = c ^ (row&7))
// -> conflict-free ds_read_b128 fragments.  W split: cols < nsplit from W1
// (width ldw), else W2 (supports fused K|V GEMM).
// ---------------------------------------------------------------------------
template <typename OutT>
__global__ __launch_bounds__(256) void gemm_mfma(
    const float* __restrict__ A, const float* __restrict__ W1,
    const float* __restrict__ W2, int ldw,
    const float* __restrict__ b1, const float* __restrict__ b2,
    OutT* __restrict__ C, int N, int K, int nsplit)
{
    __shared__ ushort16 As[128 * 64];
    __shared__ ushort16 Bs[128 * 64];

    const int tid  = threadIdx.x;
    const int lane = tid & 63, wave = tid >> 6;
    const int quad = lane >> 4, m16 = lane & 15;
    const int wm = (wave >> 1) * 64, wn = (wave & 1) * 64;
    const int gm0 = blockIdx.y * 128, gn0 = blockIdx.x * 128;

    const float* Wuse = (gn0 < nsplit) ? W1 : W2;
    const int ncol0 = (gn0 < nsplit) ? gn0 : gn0 - nsplit;

    f32x4 acc[4][4];
#pragma unroll
    for (int i = 0; i < 4; ++i)
#pragma unroll
        for (int j = 0; j < 4; ++j) acc[i][j] = (f32x4){0.f, 0.f, 0.f, 0.f};

    // staging geometry
    const int ra = tid >> 3, cla = tid & 7;            // A: row, logical k-chunk
    const int kpb = tid >> 5, nlb = tid & 31;          // B: k-pair, n-lane
    const float* Ap = A + (size_t)(gm0 + ra) * K + cla * 8;
    const float* Wp = Wuse + (size_t)(2 * kpb) * ldw + ncol0 + nlb;

    for (int k0 = 0; k0 < K; k0 += 64) {
        float4 av0[4], av1[4];
        float bv0[4][4], bv1[4][4];
#pragma unroll
        for (int t = 0; t < 4; ++t) {
            const float* ap = Ap + k0 + (size_t)(32 * t) * K;
            av0[t] = *(const float4*)ap;
            av1[t] = *(const float4*)(ap + 4);
            const float* wp = Wp + (size_t)(k0 + 16 * t) * ldw;
#pragma unroll
            for (int j = 0; j < 4; ++j) {
                bv0[t][j] = wp[32 * j];
                bv1[t][j] = wp[(size_t)ldw + 32 * j];
            }
        }
        __syncthreads();   // previous tile fully consumed
#pragma unroll
        for (int t = 0; t < 4; ++t) {
            int r = ra + 32 * t;
            uint4 st;
            st.x = pack2rn(av0[t].x, av0[t].y);
            st.y = pack2rn(av0[t].z, av0[t].w);
            st.z = pack2rn(av1[t].x, av1[t].y);
            st.w = pack2rn(av1[t].z, av1[t].w);
            *(uint4*)&As[r * 64 + ((cla ^ (r & 7)) * 8)] = st;

            int kp = kpb + 8 * t;
            int clb = kp >> 2, kq = kp & 3;
#pragma unroll
            for (int j = 0; j < 4; ++j) {
                int n = nlb + 32 * j;
                *(uint32*)&Bs[n * 64 + (clb ^ (n & 7)) * 8 + kq * 2] =
                    pack2rn(bv0[t][j], bv1[t][j]);
            }
        }
        __syncthreads();

#pragma unroll
        for (int s = 0; s < 2; ++s) {
            bf16x8 aF[4], bF[4];
            const int cl = s * 4 + quad;
#pragma unroll
            for (int i = 0; i < 4; ++i) {
                int r = wm + i * 16 + m16;
                aF[i] = *(const bf16x8*)&As[r * 64 + (cl ^ (r & 7)) * 8];
                int n = wn + i * 16 + m16;
                bF[i] = *(const bf16x8*)&Bs[n * 64 + (cl ^ (n & 7)) * 8];
            }
#pragma unroll
            for (int i = 0; i < 4; ++i)
#pragma unroll
                for (int j = 0; j < 4; ++j)
                    acc[i][j] = __builtin_amdgcn_mfma_f32_16x16x32_bf16(
                        aF[i], bF[j], acc[i][j], 0, 0, 0);
        }
    }

    // epilogue: D row = quad*4 + reg, col = lane&15
#pragma unroll
    for (int j = 0; j < 4; ++j) {
        int col = gn0 + wn + j * 16 + m16;
        float bb = (col < nsplit) ? b1[col] : b2[col - nsplit];
#pragma unroll
        for (int i = 0; i < 4; ++i) {
            int row0 = gm0 + wm + i * 16 + quad * 4;
#pragma unroll
            for (int r = 0; r < 4; ++r)
                storeC(acc[i][j][r] + bb, C + (size_t)(row0 + r) * N + col);
        }
    }
}

// ---------------------------------------------------------------------------
// RoPE in-place on fp32 Q viewed as [S, 32, 128]; interleaved pairs.
// ---------------------------------------------------------------------------
__global__ void rope_q_kernel(float* __restrict__ T, int S)
{
    int idx = blockIdx.x * blockDim.x + threadIdx.x;
    if (idx >= S * 32 * 64) return;
    int i   = idx & 63;
    int rem = idx >> 6;       // s*32 + h
    int s   = rem >> 5;
    float inv = powf(5000.0f, -(float)i / 64.0f);
    float ang = (float)s * inv;
    float cs = cosf(ang), sn = sinf(ang);
    size_t base = (size_t)rem * 128 + 2 * i;
    float tr = T[base], ti = T[base + 1];
    T[base]     = tr * cs - ti * sn;
    T[base + 1] = tr * sn + ti * cs;
}

// RoPE in-place on bf16 K = cols 0..1023 of KVb [S][2048]
__global__ void rope_k_kernel(ushort16* __restrict__ KVb, int S)
{
    int idx = blockIdx.x * blockDim.x + threadIdx.x;
    if (idx >= S * 8 * 64) return;
    int i   = idx & 63;
    int rem = idx >> 6;       // s*8 + h
    int s   = rem >> 3, h = rem & 7;
    float inv = powf(5000.0f, -(float)i / 64.0f);
    float ang = (float)s * inv;
    float cs = cosf(ang), sn = sinf(ang);
    uint32* p = (uint32*)&KVb[(size_t)s * 2048 + h * 128 + 2 * i];
    uint32 u = *p;
    float tr = blo(u), ti = bhi(u);
    *p = pack2rn(tr * cs - ti * sn, tr * sn + ti * cs);
}

// ---------------------------------------------------------------------------
// MFMA flash attention. Block = (pair of 64-row q-tiles, head); 256 thr = 4 wv.
// Grid.x = 16: block x processes q-tile (31-x) then q-tile x -> every block
// does exactly (32-x)+(x+1) = 33 KV-tile units. This kills the CU load
// imbalance of the 1-tile-per-block version (blocks sharing a CU all had the
// same causal length because 256 % 32 == 0 -> worst CU did 32x the work of
// the best; measured MfmaUtil 5.5%, occupancy 12%).
// Softmax runs in the exp2 domain: log2(e) folded into the Q pre-scale.
// Fragment conventions identical to gemm_mfma:
//   A = [row][k] bf16 16B chunks, chunk_phys = chunk ^ (row&7); B = [col][k];
//   C/D: col = lane&15, row = quad*4+reg.
// LDS: Ks[64][128], Vt[128][64], Ps[64][64] = 40 KB -> 2 blocks/CU at grid 512.
// ---------------------------------------------------------------------------
__global__ __launch_bounds__(256) void flash_attn_kernel(
    const float* __restrict__ Q, const ushort16* __restrict__ KVb,
    float* __restrict__ O)
{
    __shared__ __align__(16) ushort16 Ks[64 * 128];   // [kv][d], swizzled
    __shared__ __align__(16) ushort16 Vt[128 * 64];   // [d][kv], swizzled
    __shared__ __align__(16) ushort16 Ps[64 * 64];    // [q][kv], swizzled

    const int tid  = threadIdx.x;
    const int lane = tid & 63, wave = tid >> 6;
    const int quad = lane >> 4, m16 = lane & 15;
    const int h = (int)blockIdx.y, kvh = h >> 2;
    // 1/sqrt(128) * log2(e): softmax in exp2 domain
    const float scale = 0.08838834764831845f * 1.4426950408889634f;

    const ushort16* Kbase = KVb + kvh * 128;
    const ushort16* Vbase = KVb + 1024 + kvh * 128;

    for (int pass = 0; pass < 2; ++pass) {
        const int qi = pass ? (int)blockIdx.x : 31 - (int)blockIdx.x;
        const int q0 = qi * 64;

        // Q A-fragments to registers: row = wave*16+m16, k = ks*32+quad*8+i
        bf16x8 qa[4];
        {
            const float* qp = Q + (size_t)(q0 + wave * 16 + m16) * 4096 + h * 128 + quad * 8;
#pragma unroll
            for (int ks = 0; ks < 4; ++ks) {
                float4 a = *(const float4*)(qp + ks * 32);
                float4 b = *(const float4*)(qp + ks * 32 + 4);
                uint4 u;
                u.x = pack2rn(a.x * scale, a.y * scale);
                u.y = pack2rn(a.z * scale, a.w * scale);
                u.z = pack2rn(b.x * scale, b.y * scale);
                u.w = pack2rn(b.z * scale, b.w * scale);
                qa[ks] = *(bf16x8*)&u;
            }
        }

        f32x4 acc_o[8];
#pragma unroll
        for (int t = 0; t < 8; ++t) acc_o[t] = (f32x4){0.f, 0.f, 0.f, 0.f};
        float m_i[4], l_i[4];
#pragma unroll
        for (int r = 0; r < 4; ++r) { m_i[r] = -1e30f; l_i[r] = 0.f; }

        for (int k0 = 0; k0 <= q0; k0 += 64) {
            __syncthreads();   // prev tile's (and prev pass's) LDS reads done

            // stage K -> Ks[kv][d]: straight 16B copies, swizzled dest
#pragma unroll
            for (int it = 0; it < 4; ++it) {
                int idx = tid + it * 256;
                int row = idx >> 4, c = idx & 15;
                *(uint4*)&Ks[row * 128 + ((c ^ (row & 7)) * 8)] =
                    *(const uint4*)(Kbase + (size_t)(k0 + row) * 2048 + c * 8);
            }
            // stage V -> Vt[d][kv] via v_perm pair interleave.
#pragma unroll
            for (int it = 0; it < 2; ++it) {
                int idx = tid + it * 256;
                int rp  = idx & 31;           // kv row-pair 0..31
                int dcb = (idx >> 5) * 8;     // d base 0..120
                const ushort16* p0 = Vbase + (size_t)(k0 + 2 * rp) * 2048 + dcb;
                uint4 a = *(const uint4*)p0;
                uint4 b = *(const uint4*)(p0 + 2048);
                uint32 aw[4] = {a.x, a.y, a.z, a.w}, bw[4] = {b.x, b.y, b.z, b.w};
                int cc = rp >> 2, cbase = 2 * (rp & 3);
#pragma unroll
                for (int t = 0; t < 4; ++t) {
                    int d0 = dcb + 2 * t, d1 = d0 + 1;
                    *(uint32*)&Vt[d0 * 64 + ((cc ^ (d0 & 7)) * 8) + cbase] =
                        __builtin_amdgcn_perm(bw[t], aw[t], 0x05040100);
                    *(uint32*)&Vt[d1 * 64 + ((cc ^ (d1 & 7)) * 8) + cbase] =
                        __builtin_amdgcn_perm(bw[t], aw[t], 0x07060302);
                }
            }
            __syncthreads();

            // S = Q @ K^T : wave strip 16(q) x 64(kv), 16 MFMAs
            f32x4 sacc[4];
#pragma unroll
            for (int j = 0; j < 4; ++j) sacc[j] = (f32x4){0.f, 0.f, 0.f, 0.f};
            __builtin_amdgcn_s_setprio(1);
#pragma unroll
            for (int ks = 0; ks < 4; ++ks) {
#pragma unroll
                for (int j = 0; j < 4; ++j) {
                    int n = j * 16 + m16;
                    bf16x8 kb = *(const bf16x8*)&Ks[n * 128 + (((ks * 4 + quad) ^ (n & 7)) * 8)];
                    sacc[j] = __builtin_amdgcn_mfma_f32_16x16x32_bf16(qa[ks], kb, sacc[j], 0, 0, 0);
                }
            }
            __builtin_amdgcn_s_setprio(0);

            if (k0 == q0) {   // diagonal tile: causal mask
                int qr = wave * 16 + quad * 4;
#pragma unroll
                for (int j = 0; j < 4; ++j) {
                    int kvl = j * 16 + m16;
#pragma unroll
                    for (int r = 0; r < 4; ++r)
                        if (kvl > qr + r) sacc[j][r] = -1e30f;
                }
            }

            // online softmax (exp2 domain; row group = 16 lanes of this quad)
#pragma unroll
            for (int r = 0; r < 4; ++r) {
                float rm = fmaxf(fmaxf(sacc[0][r], sacc[1][r]), fmaxf(sacc[2][r], sacc[3][r]));
                rm = fmaxf(rm, __shfl_xor(rm, 1));
                rm = fmaxf(rm, __shfl_xor(rm, 2));
                rm = fmaxf(rm, __shfl_xor(rm, 4));
                rm = fmaxf(rm, __shfl_xor(rm, 8));
                float mnew = fmaxf(m_i[r], rm);
                float al = exp2f(m_i[r] - mnew);
                float rs = 0.f;
#pragma unroll
                for (int j = 0; j < 4; ++j) {
                    float pv = exp2f(sacc[j][r] - mnew);
                    sacc[j][r] = pv;
                    rs += pv;
                }
                rs += __shfl_xor(rs, 1);
                rs += __shfl_xor(rs, 2);
                rs += __shfl_xor(rs, 4);
                rs += __shfl_xor(rs, 8);
                l_i[r] = l_i[r] * al + rs;
                m_i[r] = mnew;
                int q = wave * 16 + quad * 4 + r;
#pragma unroll
                for (int j = 0; j < 4; ++j) {      // P -> Ps (wave-private rows)
                    int kv = j * 16 + m16;
                    Ps[q * 64 + (((kv >> 3) ^ (q & 7)) * 8) + (kv & 7)] = f2bf(sacc[j][r]);
                }
#pragma unroll
                for (int t = 0; t < 8; ++t) acc_o[t][r] *= al;
            }

            // O += P @ V : 16 MFMAs (A = Ps rows wave*16+m16, B = Vt)
            int qrow = wave * 16 + m16;
#pragma unroll
            for (int ks2 = 0; ks2 < 2; ++ks2) {
                bf16x8 pa = *(const bf16x8*)&Ps[qrow * 64 + (((ks2 * 4 + quad) ^ (qrow & 7)) * 8)];
                __builtin_amdgcn_s_setprio(1);
#pragma unroll
                for (int t = 0; t < 8; ++t) {
                    int d = t * 16 + m16;
                    bf16x8 vb = *(const bf16x8*)&Vt[d * 64 + (((ks2 * 4 + quad) ^ (d & 7)) * 8)];
                    acc_o[t] = __builtin_amdgcn_mfma_f32_16x16x32_bf16(pa, vb, acc_o[t], 0, 0, 0);
                }
                __builtin_amdgcn_s_setprio(0);
            }
        }

        // epilogue: O /= l.  row = q0+wave*16+quad*4+r, col = h*128+t*16+m16
        float* op = O + (size_t)(q0 + wave * 16 + quad * 4) * 4096 + h * 128 + m16;
#pragma unroll
        for (int r = 0; r < 4; ++r) {
            float inv = 1.0f / l_i[r];
#pragma unroll
            for (int t = 0; t < 8; ++t)
                op[(size_t)r * 4096 + t * 16] = acc_o[t][r] * inv;
        }
    }
}

// ---------------------------------------------------------------------------
extern "C" void kernel_launch(void* const* d_in, const int* in_sizes, int n_in,
                              void* d_out, int out_size, void* d_ws, size_t ws_size,
                              hipStream_t stream)
{
    const float* x  = (const float*)d_in[0];
    const float* y  = (const float*)d_in[1];
    const float* Wq = (const float*)d_in[2];
    const float* bq = (const float*)d_in[3];
    const float* Wk = (const float*)d_in[4];
    const float* bk = (const float*)d_in[5];
    const float* Wv = (const float*)d_in[6];
    const float* bv = (const float*)d_in[7];
    const float* Wo = (const float*)d_in[8];
    const float* bo = (const float*)d_in[9];
    float* out = (float*)d_out;

    const int S = 2048, D = 4096;

    // Q fp32 lives in d_out (consumed by attn before final GEMM overwrites).
    float* Q = out;
    char* ws = (char*)d_ws;
    float*    Ao  = (float*)ws;                            // 32 MB fp32
    ushort16* KVb = (ushort16*)(ws + 34ull * 1024 * 1024); // 8 MB bf16 [S][2048]

    // Q = x @ Wq + bq   (fp32 out, 512 blocks)
    gemm_mfma<float><<<dim3(32, 16), 256, 0, stream>>>(
        x, Wq, Wq, D, bq, bq, Q, D, D, D);
    // KV = y @ [Wk|Wv] + [bk|bv]  (bf16 out, fused N=2048)
    gemm_mfma<ushort16><<<dim3(16, 16), 256, 0, stream>>>(
        y, Wk, Wv, 1024, bk, bv, KVb, 2048, D, 1024);

    rope_q_kernel<<<(S * 32 * 64 + 255) / 256, 256, 0, stream>>>(Q, S);
    rope_k_kernel<<<(S * 8 * 64 + 255) / 256, 256, 0, stream>>>(KVb, S);

    flash_attn_kernel<<<dim3(16, 32), 256, 0, stream>>>(Q, KVb, Ao);

    // out = Ao @ Wo + bo
    gemm_mfma<float><<<dim3(32, 16), 256, 0, stream>>>(
        Ao, Wo, Wo, D, bo, bo, out, D, D, D);
}

// Round 3
// 664.931 us; speedup vs baseline: 2.3906x; 1.0248x over previous
//
#include <hip/hip_runtime.h>
#include <hip/hip_bf16.h>

typedef unsigned int uint32;
typedef unsigned short ushort16;
typedef __attribute__((ext_vector_type(8))) __bf16 bf16x8;
typedef __attribute__((ext_vector_type(4))) float f32x4;

__device__ __forceinline__ ushort16 f2bf(float f) {
    uint32 u = __float_as_uint(f);
    u += 0x7fff + ((u >> 16) & 1);       // round-to-nearest-even
    return (ushort16)(u >> 16);
}
// pack two fp32 -> dword of 2 bf16 (a in low half), round-to-nearest (+0x8000)
__device__ __forceinline__ uint32 pack2rn(float a, float b) {
    uint32 ua = __float_as_uint(a) + 0x8000u;
    uint32 ub = __float_as_uint(b) + 0x8000u;
    return __builtin_amdgcn_perm(ub, ua, 0x07060302);  // [a.hi16, b.hi16]
}
__device__ __forceinline__ float blo(uint32 u) { return __uint_as_float(u << 16); }
__device__ __forceinline__ float bhi(uint32 u) { return __uint_as_float(u & 0xffff0000u); }

__device__ __forceinline__ void storeC(float v, float* p) { *p = v; }
__device__ __forceinline__ void storeC(float v, ushort16* p) { *p = f2bf(v); }

// async 16B global -> LDS (linear dest: wave-uniform base + lane*16)
__device__ __forceinline__ void gload_lds16(const void* g, void* l) {
    __builtin_amdgcn_global_load_lds(
        (const __attribute__((address_space(1))) unsigned int*)g,
        (__attribute__((address_space(3))) unsigned int*)l, 16, 0, 0);
}

// ---------------------------------------------------------------------------
// fp32 -> bf16 bulk convert (8 elems/thread)
// ---------------------------------------------------------------------------
__global__ __launch_bounds__(256) void conv_bf16(
    const float* __restrict__ X, ushort16* __restrict__ Xb, int n8)
{
    int idx = blockIdx.x * blockDim.x + threadIdx.x;
    if (idx >= n8) return;
    float4 a = ((const float4*)X)[2 * idx];
    float4 b = ((const float4*)X)[2 * idx + 1];
    uint4 u;
    u.x = pack2rn(a.x, a.y); u.y = pack2rn(a.z, a.w);
    u.z = pack2rn(b.x, b.y); u.w = pack2rn(b.z, b.w);
    ((uint4*)Xb)[idx] = u;
}

// ---------------------------------------------------------------------------
// W [K=4096][N] fp32  ->  Wt [N][K=4096] bf16 (dest base pre-offset by caller).
// 64x64 tiles via LDS; both global sides coalesced.
// ---------------------------------------------------------------------------
__global__ __launch_bounds__(256) void transpose_w_bf16(
    const float* __restrict__ W, ushort16* __restrict__ Wt, int N)
{
    __shared__ float tile[64][65];
    const int k0 = blockIdx.x * 64, n0 = blockIdx.y * 64;
#pragma unroll
    for (int it = 0; it < 16; ++it) {
        int idx = threadIdx.x + it * 256;
        int r = idx >> 6, c = idx & 63;
        tile[r][c] = W[(size_t)(k0 + r) * N + n0 + c];
    }
    __syncthreads();
#pragma unroll
    for (int it = 0; it < 8; ++it) {
        int idx = threadIdx.x + it * 256;
        int nr = idx >> 5, kp = idx & 31;          // 2 k's per thread
        uint32 u = pack2rn(tile[2 * kp][nr], tile[2 * kp + 1][nr]);
        *(uint32*)&Wt[(size_t)(n0 + nr) * 4096 + k0 + 2 * kp] = u;
    }
}

// ---------------------------------------------------------------------------
// MFMA GEMM (m97 structure): C[M,N] = A[M,K] @ B[N,K]^T + bias, bf16 inputs.
// 128x128 tile, BK=64, 4 waves x (4x4 grid of 16x16x32 bf16 MFMA).
// Staging via global_load_lds (16B): LDS dest is LINEAR (row*128B + chunk*16B);
// the XOR swizzle (chunk_phys = chunk ^ (row&7)) is pre-applied to the per-lane
// GLOBAL source address (rule: swizzle both sides or neither; gload_lds writes
// base+lane*16 only).  Fragment reads identical to the proven swizzled layout.
// bias: col < nsplit -> b1[col], else b2[col-nsplit] (fused K|V GEMM).
// ---------------------------------------------------------------------------
template <typename OutT>
__global__ __launch_bounds__(256) void gemm_mfma(
    const ushort16* __restrict__ A, const ushort16* __restrict__ B,
    const float* __restrict__ b1, const float* __restrict__ b2,
    OutT* __restrict__ C, int N, int K, int nsplit)
{
    __shared__ __align__(16) ushort16 As[128 * 64];
    __shared__ __align__(16) ushort16 Bs[128 * 64];

    const int tid  = threadIdx.x;
    const int lane = tid & 63, wave = tid >> 6;
    const int quad = lane >> 4, m16 = lane & 15;
    const int wm = (wave >> 1) * 64, wn = (wave & 1) * 64;
    const int gm0 = blockIdx.y * 128, gn0 = blockIdx.x * 128;

    f32x4 acc[4][4];
#pragma unroll
    for (int i = 0; i < 4; ++i)
#pragma unroll
        for (int j = 0; j < 4; ++j) acc[i][j] = (f32x4){0.f, 0.f, 0.f, 0.f};

    // DMA staging: wave w covers tile rows w*32..w*32+31, 4 calls x 8 rows.
    // lane l -> row_in_call = l>>3, phys chunk = l&7,
    // logical chunk = (l&7) ^ ((l>>3)&7)  (since call-base rows are %8 == 0).
    const int rl = lane >> 3, cl = lane & 7;
    const int clog = cl ^ (rl & 7);
    const ushort16* Ag = A + (size_t)(gm0 + wave * 32 + rl) * K + clog * 8;
    const ushort16* Bg = B + (size_t)(gn0 + wave * 32 + rl) * K + clog * 8;
    char* AsW = (char*)As + wave * 4096;
    char* BsW = (char*)Bs + wave * 4096;

    for (int k0 = 0; k0 < K; k0 += 64) {
        __syncthreads();   // previous tile fully consumed
#pragma unroll
        for (int i = 0; i < 4; ++i) {
            gload_lds16(Ag + (size_t)(8 * i) * K, AsW + i * 1024);
            gload_lds16(Bg + (size_t)(8 * i) * K, BsW + i * 1024);
        }
        Ag += 64; Bg += 64;
        __syncthreads();   // compiler drains vmcnt before barrier -> data ready

#pragma unroll
        for (int s = 0; s < 2; ++s) {
            bf16x8 aF[4], bF[4];
            const int cr = s * 4 + quad;
#pragma unroll
            for (int i = 0; i < 4; ++i) {
                int r = wm + i * 16 + m16;
                aF[i] = *(const bf16x8*)&As[r * 64 + ((cr ^ (r & 7)) * 8)];
                int n = wn + i * 16 + m16;
                bF[i] = *(const bf16x8*)&Bs[n * 64 + ((cr ^ (n & 7)) * 8)];
            }
            __builtin_amdgcn_s_setprio(1);
#pragma unroll
            for (int i = 0; i < 4; ++i)
#pragma unroll
                for (int j = 0; j < 4; ++j)
                    acc[i][j] = __builtin_amdgcn_mfma_f32_16x16x32_bf16(
                        aF[i], bF[j], acc[i][j], 0, 0, 0);
            __builtin_amdgcn_s_setprio(0);
        }
    }

    // epilogue: D row = quad*4 + reg, col = lane&15
#pragma unroll
    for (int j = 0; j < 4; ++j) {
        int col = gn0 + wn + j * 16 + m16;
        float bb = (col < nsplit) ? b1[col] : b2[col - nsplit];
#pragma unroll
        for (int i = 0; i < 4; ++i) {
            int row0 = gm0 + wm + i * 16 + quad * 4;
#pragma unroll
            for (int r = 0; r < 4; ++r)
                storeC(acc[i][j][r] + bb, C + (size_t)(row0 + r) * N + col);
        }
    }
}

// ---------------------------------------------------------------------------
// RoPE: read fp32 Q [S,32,128] (interleaved pairs), apply rope, fold in
// softmax scale (1/sqrt(128) * log2e), emit bf16 Qb [S][4096].
// Same single-rounding as before (round happens after rope+scale).
// ---------------------------------------------------------------------------
__global__ void rope_q_kernel(const float* __restrict__ T,
                              ushort16* __restrict__ Qb, int S)
{
    int idx = blockIdx.x * blockDim.x + threadIdx.x;
    if (idx >= S * 32 * 64) return;
    int i   = idx & 63;
    int rem = idx >> 6;       // s*32 + h
    int s   = rem >> 5;
    float inv = powf(5000.0f, -(float)i / 64.0f);
    float ang = (float)s * inv;
    float cs = cosf(ang), sn = sinf(ang);
    const float sc = 0.08838834764831845f * 1.4426950408889634f;
    size_t base = (size_t)rem * 128 + 2 * i;
    float tr = T[base], ti = T[base + 1];
    *(uint32*)&Qb[base] = pack2rn((tr * cs - ti * sn) * sc,
                                  (tr * sn + ti * cs) * sc);
}

// RoPE in-place on bf16 K = cols 0..1023 of KVb [S][2048]
__global__ void rope_k_kernel(ushort16* __restrict__ KVb, int S)
{
    int idx = blockIdx.x * blockDim.x + threadIdx.x;
    if (idx >= S * 8 * 64) return;
    int i   = idx & 63;
    int rem = idx >> 6;       // s*8 + h
    int s   = rem >> 3, h = rem & 7;
    float inv = powf(5000.0f, -(float)i / 64.0f);
    float ang = (float)s * inv;
    float cs = cosf(ang), sn = sinf(ang);
    uint32* p = (uint32*)&KVb[(size_t)s * 2048 + h * 128 + 2 * i];
    uint32 u = *p;
    float tr = blo(u), ti = bhi(u);
    *p = pack2rn(tr * cs - ti * sn, tr * sn + ti * cs);
}

// ---------------------------------------------------------------------------
// MFMA flash attention. Block = (pair of 64-row q-tiles, head); 256 thr = 4 wv.
// Grid.x = 16: block x processes q-tile (31-x) then q-tile x -> every block
// does exactly 33 KV-tile units (balanced by construction).
// Qb bf16 [S][4096] pre-scaled by 1/sqrt(128)*log2e; softmax in exp2 domain.
// O written bf16 (A-operand of the final GEMM).
// LDS: Ks[64][128], Vt[128][64], Ps[64][64] = 40 KB.
// ---------------------------------------------------------------------------
__global__ __launch_bounds__(256) void flash_attn_kernel(
    const ushort16* __restrict__ Qb, const ushort16* __restrict__ KVb,
    ushort16* __restrict__ O)
{
    __shared__ __align__(16) ushort16 Ks[64 * 128];   // [kv][d], swizzled
    __shared__ __align__(16) ushort16 Vt[128 * 64];   // [d][kv], swizzled
    __shared__ __align__(16) ushort16 Ps[64 * 64];    // [q][kv], swizzled

    const int tid  = threadIdx.x;
    const int lane = tid & 63, wave = tid >> 6;
    const int quad = lane >> 4, m16 = lane & 15;
    const int h = (int)blockIdx.y, kvh = h >> 2;

    const ushort16* Kbase = KVb + kvh * 128;
    const ushort16* Vbase = KVb + 1024 + kvh * 128;

    for (int pass = 0; pass < 2; ++pass) {
        const int qi = pass ? (int)blockIdx.x : 31 - (int)blockIdx.x;
        const int q0 = qi * 64;

        // Q A-fragments: direct bf16 16B loads (pre-scaled by rope_q)
        bf16x8 qa[4];
        {
            const ushort16* qp = Qb + (size_t)(q0 + wave * 16 + m16) * 4096
                               + h * 128 + quad * 8;
#pragma unroll
            for (int ks = 0; ks < 4; ++ks)
                qa[ks] = *(const bf16x8*)(qp + ks * 32);
        }

        f32x4 acc_o[8];
#pragma unroll
        for (int t = 0; t < 8; ++t) acc_o[t] = (f32x4){0.f, 0.f, 0.f, 0.f};
        float m_i[4], l_i[4];
#pragma unroll
        for (int r = 0; r < 4; ++r) { m_i[r] = -1e30f; l_i[r] = 0.f; }

        for (int k0 = 0; k0 <= q0; k0 += 64) {
            __syncthreads();   // prev tile's (and prev pass's) LDS reads done

            // stage K -> Ks[kv][d]: straight 16B copies, swizzled dest
#pragma unroll
            for (int it = 0; it < 4; ++it) {
                int idx = tid + it * 256;
                int row = idx >> 4, c = idx & 15;
                *(uint4*)&Ks[row * 128 + ((c ^ (row & 7)) * 8)] =
                    *(const uint4*)(Kbase + (size_t)(k0 + row) * 2048 + c * 8);
            }
            // stage V -> Vt[d][kv] via v_perm pair interleave.
#pragma unroll
            for (int it = 0; it < 2; ++it) {
                int idx = tid + it * 256;
                int rp  = idx & 31;           // kv row-pair 0..31
                int dcb = (idx >> 5) * 8;     // d base 0..120
                const ushort16* p0 = Vbase + (size_t)(k0 + 2 * rp) * 2048 + dcb;
                uint4 a = *(const uint4*)p0;
                uint4 b = *(const uint4*)(p0 + 2048);
                uint32 aw[4] = {a.x, a.y, a.z, a.w}, bw[4] = {b.x, b.y, b.z, b.w};
                int cc = rp >> 2, cbase = 2 * (rp & 3);
#pragma unroll
                for (int t = 0; t < 4; ++t) {
                    int d0 = dcb + 2 * t, d1 = d0 + 1;
                    *(uint32*)&Vt[d0 * 64 + ((cc ^ (d0 & 7)) * 8) + cbase] =
                        __builtin_amdgcn_perm(bw[t], aw[t], 0x05040100);
                    *(uint32*)&Vt[d1 * 64 + ((cc ^ (d1 & 7)) * 8) + cbase] =
                        __builtin_amdgcn_perm(bw[t], aw[t], 0x07060302);
                }
            }
            __syncthreads();

            // S = Q @ K^T : wave strip 16(q) x 64(kv), 16 MFMAs
            f32x4 sacc[4];
#pragma unroll
            for (int j = 0; j < 4; ++j) sacc[j] = (f32x4){0.f, 0.f, 0.f, 0.f};
            __builtin_amdgcn_s_setprio(1);
#pragma unroll
            for (int ks = 0; ks < 4; ++ks) {
#pragma unroll
                for (int j = 0; j < 4; ++j) {
                    int n = j * 16 + m16;
                    bf16x8 kb = *(const bf16x8*)&Ks[n * 128 + (((ks * 4 + quad) ^ (n & 7)) * 8)];
                    sacc[j] = __builtin_amdgcn_mfma_f32_16x16x32_bf16(qa[ks], kb, sacc[j], 0, 0, 0);
                }
            }
            __builtin_amdgcn_s_setprio(0);

            if (k0 == q0) {   // diagonal tile: causal mask
                int qr = wave * 16 + quad * 4;
#pragma unroll
                for (int j = 0; j < 4; ++j) {
                    int kvl = j * 16 + m16;
#pragma unroll
                    for (int r = 0; r < 4; ++r)
                        if (kvl > qr + r) sacc[j][r] = -1e30f;
                }
            }

            // online softmax (exp2 domain; row group = 16 lanes of this quad)
#pragma unroll
            for (int r = 0; r < 4; ++r) {
                float rm = fmaxf(fmaxf(sacc[0][r], sacc[1][r]), fmaxf(sacc[2][r], sacc[3][r]));
                rm = fmaxf(rm, __shfl_xor(rm, 1));
                rm = fmaxf(rm, __shfl_xor(rm, 2));
                rm = fmaxf(rm, __shfl_xor(rm, 4));
                rm = fmaxf(rm, __shfl_xor(rm, 8));
                float mnew = fmaxf(m_i[r], rm);
                float al = exp2f(m_i[r] - mnew);
                float rs = 0.f;
#pragma unroll
                for (int j = 0; j < 4; ++j) {
                    float pv = exp2f(sacc[j][r] - mnew);
                    sacc[j][r] = pv;
                    rs += pv;
                }
                rs += __shfl_xor(rs, 1);
                rs += __shfl_xor(rs, 2);
                rs += __shfl_xor(rs, 4);
                rs += __shfl_xor(rs, 8);
                l_i[r] = l_i[r] * al + rs;
                m_i[r] = mnew;
                int q = wave * 16 + quad * 4 + r;
#pragma unroll
                for (int j = 0; j < 4; ++j) {      // P -> Ps (wave-private rows)
                    int kv = j * 16 + m16;
                    Ps[q * 64 + (((kv >> 3) ^ (q & 7)) * 8) + (kv & 7)] = f2bf(sacc[j][r]);
                }
#pragma unroll
                for (int t = 0; t < 8; ++t) acc_o[t][r] *= al;
            }

            // O += P @ V : 16 MFMAs (A = Ps rows wave*16+m16, B = Vt)
            int qrow = wave * 16 + m16;
#pragma unroll
            for (int ks2 = 0; ks2 < 2; ++ks2) {
                bf16x8 pa = *(const bf16x8*)&Ps[qrow * 64 + (((ks2 * 4 + quad) ^ (qrow & 7)) * 8)];
                __builtin_amdgcn_s_setprio(1);
#pragma unroll
                for (int t = 0; t < 8; ++t) {
                    int d = t * 16 + m16;
                    bf16x8 vb = *(const bf16x8*)&Vt[d * 64 + (((ks2 * 4 + quad) ^ (d & 7)) * 8)];
                    acc_o[t] = __builtin_amdgcn_mfma_f32_16x16x32_bf16(pa, vb, acc_o[t], 0, 0, 0);
                }
                __builtin_amdgcn_s_setprio(0);
            }
        }

        // epilogue: O = bf16(acc/l).  row = q0+wave*16+quad*4+r, col = h*128+t*16+m16
        ushort16* op = O + (size_t)(q0 + wave * 16 + quad * 4) * 4096 + h * 128 + m16;
#pragma unroll
        for (int r = 0; r < 4; ++r) {
            float inv = 1.0f / l_i[r];
#pragma unroll
            for (int t = 0; t < 8; ++t)
                op[(size_t)r * 4096 + t * 16] = f2bf(acc_o[t][r] * inv);
        }
    }
}

// ---------------------------------------------------------------------------
extern "C" void kernel_launch(void* const* d_in, const int* in_sizes, int n_in,
                              void* d_out, int out_size, void* d_ws, size_t ws_size,
                              hipStream_t stream)
{
    const float* x  = (const float*)d_in[0];
    const float* y  = (const float*)d_in[1];
    const float* Wq = (const float*)d_in[2];
    const float* bq = (const float*)d_in[3];
    const float* Wk = (const float*)d_in[4];
    const float* bk = (const float*)d_in[5];
    const float* Wv = (const float*)d_in[6];
    const float* bv = (const float*)d_in[7];
    const float* Wo = (const float*)d_in[8];
    const float* bo = (const float*)d_in[9];
    float* out = (float*)d_out;

    const int S = 2048, D = 4096;
    const size_t MB = 1024 * 1024;

    // workspace layout (120 MB):
    char* ws = (char*)d_ws;
    ushort16* xb   = (ushort16*)(ws);             // 16 MB, reused as Qb
    ushort16* yb   = (ushort16*)(ws + 16 * MB);   // 16 MB, reused as Ao
    ushort16* Wqt  = (ushort16*)(ws + 32 * MB);   // 32 MB [4096][4096]
    ushort16* Wkvt = (ushort16*)(ws + 64 * MB);   // 16 MB [2048][4096] = Wk^T|Wv^T
    ushort16* Wot  = (ushort16*)(ws + 80 * MB);   // 32 MB [4096][4096]
    ushort16* KVb  = (ushort16*)(ws + 112 * MB);  //  8 MB [S][2048]
    ushort16* Qb   = xb;                          // alias (xb dead after Q GEMM)
    ushort16* Ao   = yb;                          // alias (yb dead after KV GEMM)
    float*    Q    = out;                         // fp32 Q lives in d_out

    const int n8 = S * D / 8;
    conv_bf16<<<n8 / 256, 256, 0, stream>>>(x, xb, n8);
    conv_bf16<<<n8 / 256, 256, 0, stream>>>(y, yb, n8);
    transpose_w_bf16<<<dim3(64, 64), 256, 0, stream>>>(Wq, Wqt, D);
    transpose_w_bf16<<<dim3(64, 16), 256, 0, stream>>>(Wk, Wkvt, 1024);
    transpose_w_bf16<<<dim3(64, 16), 256, 0, stream>>>(Wv, Wkvt + (size_t)1024 * 4096, 1024);
    transpose_w_bf16<<<dim3(64, 64), 256, 0, stream>>>(Wo, Wot, D);

    // Q = x @ Wq + bq   (fp32 out to d_out)
    gemm_mfma<float><<<dim3(32, 16), 256, 0, stream>>>(
        xb, Wqt, bq, bq, Q, D, D, D);
    // KV = y @ [Wk|Wv] + [bk|bv]  (bf16 out, fused N=2048)
    gemm_mfma<ushort16><<<dim3(16, 16), 256, 0, stream>>>(
        yb, Wkvt, bk, bv, KVb, 2048, D, 1024);

    rope_q_kernel<<<(S * 32 * 64 + 255) / 256, 256, 0, stream>>>(Q, Qb, S);
    rope_k_kernel<<<(S * 8 * 64 + 255) / 256, 256, 0, stream>>>(KVb, S);

    flash_attn_kernel<<<dim3(16, 32), 256, 0, stream>>>(Qb, KVb, Ao);

    // out = Ao @ Wo + bo
    gemm_mfma<float><<<dim3(32, 16), 256, 0, stream>>>(
        Ao, Wot, bo, bo, out, D, D, D);
}